// Round 7
// baseline (278.626 us; speedup 1.0000x reference)
//
#include <hip/hip_runtime.h>
#include <hip/hip_bf16.h>

#define BB   2
#define NN   128
#define SS   4
#define DGG  8
#define CIN  4
#define COUT 8
#define HH   32

typedef __attribute__((ext_vector_type(4))) float          fvec4;
typedef __attribute__((ext_vector_type(8))) unsigned short usvec8;
typedef __attribute__((ext_vector_type(2))) __fp16         half2v;

__device__ __forceinline__ float bf2f(unsigned short u) {
    return __uint_as_float(((unsigned int)u) << 16);
}
__device__ __forceinline__ float silu_f(float x) {
    float e = __builtin_amdgcn_exp2f(x * -1.44269504f);
    return x * __builtin_amdgcn_rcpf(1.0f + e);
}
__device__ __forceinline__ float exp_f(float x) {
    return __builtin_amdgcn_exp2f(x * 1.44269504f);
}

#if __has_builtin(__builtin_amdgcn_fdot2)
__device__ __forceinline__ float FDOT2(half2v a, half2v b, float c) {
    return __builtin_amdgcn_fdot2(a, b, c, false);
}
#else
__device__ __forceinline__ float FDOT2(half2v a, half2v b, float c) {
    return (float)a[0] * (float)b[0] + (float)a[1] * (float)b[1] + c;
}
#endif

__device__ __forceinline__ half2v upk(unsigned int u) {
    union { unsigned int u; half2v h; } x; x.u = u; return x.h;
}
__device__ __forceinline__ unsigned int pk2u(float a, float b) {
#if __has_builtin(__builtin_amdgcn_cvt_pkrtz)
    half2v h = __builtin_amdgcn_cvt_pkrtz(a, b);
#else
    half2v h; h[0] = (__fp16)a; h[1] = (__fp16)b;
#endif
    union { half2v h; unsigned int u; } x; x.h = h; return x.u;
}

__device__ __forceinline__ float loadS(const void* p, int idx, int fmode) {
    return fmode ? bf2f(((const unsigned short*)p)[idx])
                 : ((const float*)p)[idx];
}
__device__ __forceinline__ void load8(const void* p, int base, int fmode, float* dst) {
    if (fmode) {
        usvec8 v = *(const usvec8*)((const unsigned short*)p + base);
#pragma unroll
        for (int d = 0; d < 8; ++d) dst[d] = bf2f(v[d]);
    } else {
        fvec4 a = *(const fvec4*)((const float*)p + base);
        fvec4 b = *(const fvec4*)((const float*)p + base + 4);
        dst[0] = a[0]; dst[1] = a[1]; dst[2] = a[2]; dst[3] = a[3];
        dst[4] = b[0]; dst[5] = b[1]; dst[6] = b[2]; dst[7] = b[3];
    }
}
__device__ __forceinline__ int load_mask(const void* p, int idx, int mmode) {
    if (mmode == 0) return ((const int*)p)[idx] != 0;
    if (mmode == 1) return ((const unsigned short*)p)[idx] != 0;
    if (mmode == 2) return ((const unsigned char*)p)[idx] != 0;
    return ((const unsigned int*)p)[idx] != 0;
}

__device__ __forceinline__ void stage_pk(unsigned int* dst, const void* src, int eoff,
                                         int pairs, int fmode, int tid) {
    if (fmode) {
        const unsigned short* s = (const unsigned short*)src + eoff;
        for (int x = tid; x < pairs; x += 256)
            dst[x] = pk2u(bf2f(s[2 * x]), bf2f(s[2 * x + 1]));
    } else {
        const float* s = (const float*)src + eoff;
        for (int x = tid; x < pairs; x += 256)
            dst[x] = pk2u(s[2 * x], s[2 * x + 1]);
    }
}
__device__ __forceinline__ void copy_arr(float* sm, const void* src, int off, int eoff,
                                         int cnt, int fmode, int tid) {
    if (fmode) {
        const unsigned short* s = (const unsigned short*)src + eoff;
        for (int x = tid; x < cnt; x += 256) sm[off + x] = bf2f(s[x]);
    } else {
        const float* s = (const float*)src + eoff;
        for (int x = tid; x < cnt; x += 256) sm[off + x] = s[x];
    }
}

// LDS layout (u32 units) — single channel per block
#define U_YW1  0      // 32 pairs
#define U_GW1  32     // 128 pairs
#define U_YW2  160    // 512 pairs
#define U_GW2  672    // 512 pairs
#define F_YB1  1184   // 32 floats
#define F_YB2  1216
#define F_YW3  1248
#define F_GB1  1280
#define F_GB2  1312
#define F_GW3  1344
#define F_YB3  1376   // 1
#define F_GB3  1377   // 1
#define F_RED  1378   // 16: [4 waves][2 s1l][N,D]
#define F_MODE 1394   // 2 ints
#define U_TOTAL 1396  // 5584 B -> up to 8 blocks/CU on LDS

// 2048 blocks: blk = bn*8 + ci*2 + s1h.  256 threads: tid = n2b*8 + s1l*4 + s2.
// Each thread: 1 channel, P=4 positions (n2 = n2b + p*32, fully unrolled —
// runtime position loops re-trigger scratch spill, round-5 lesson), weight
// LDS reads per position-channel unchanged vs round 6 (channel-split, not
// position-split — round-3 lesson).  2048 blocks lift the grid-limited
// occupancy (round 6: 1024 blocks = 16 waves/CU cap, VALUBusy stuck at 80%).
// Single launch: inline dtype detect + atomic-flag cross-block finalize
// (saves ~2x16us dispatch overhead measured across rounds 2/6).
__global__ __launch_bounds__(256, 4) void emha_fused(
    const void* __restrict__ g_pw, const void* __restrict__ g_coset,
    const void* __restrict__ g_mask,
    const void* yW1, const void* yb1, const void* yW2, const void* yb2,
    const void* yW3, const void* yb3,
    const void* gW1, const void* gb1, const void* gW2, const void* gb2,
    const void* gW3, const void* gb3,
    const void* wout, float* part, unsigned int* flags, void* outp)
{
    __shared__ unsigned int smu[U_TOTAL];
    float* smf = (float*)smu;
    int*   smi = (int*)smu;
    const int tid = threadIdx.x;

    // ---- inline dtype detection (wave 0) ----
    if (tid < 64) {
        const unsigned short* cu = (const unsigned short*)g_coset;
        unsigned short v = cu[2 * tid];
        int e = (v >> 7) & 0xFF;
        int hits = __popcll(__ballot(e >= 110 && e <= 135));
        int fmode_ = (hits > 32) ? 1 : 0;
        const unsigned short* mu = (const unsigned short*)g_mask;
        int evenBF = 0, any3 = 0, anyByte = 0;
        for (int r = 0; r < 8; ++r) {
            int idx = tid + r * 64;
            unsigned short m = mu[idx];
            if (m == 0x3F80) { any3 = 1; if (!(idx & 1)) evenBF = 1; }
            if (m == 0x0101 || m == 0x0100) anyByte = 1;
        }
        evenBF  = (__ballot(evenBF)  != 0ull);
        any3    = (__ballot(any3)    != 0ull);
        anyByte = (__ballot(anyByte) != 0ull);
        if (tid == 0) {
            smi[F_MODE]     = fmode_;
            smi[F_MODE + 1] = evenBF ? 1 : (any3 ? 3 : (anyByte ? 2 : 0));
        }
    }
    __syncthreads();
    const int fmode = smi[F_MODE];
    const int mmode = smi[F_MODE + 1];

    const int blk = blockIdx.x;
    const int bn  = blk >> 3;        // b*128 + n1
    const int sub = blk & 7;
    const int ci  = sub >> 1;        // channel
    const int s1h = sub & 1;

    // ---- stage this channel's weights as packed f16 ----
    stage_pk(&smu[U_YW1], yW1, ci * 64,   32,  fmode, tid);
    stage_pk(&smu[U_GW1], gW1, ci * 256,  128, fmode, tid);
    stage_pk(&smu[U_YW2], yW2, ci * 1024, 512, fmode, tid);
    stage_pk(&smu[U_GW2], gW2, ci * 1024, 512, fmode, tid);
    copy_arr(smf, yb1, F_YB1, ci * 32, 32, fmode, tid);
    copy_arr(smf, yb2, F_YB2, ci * 32, 32, fmode, tid);
    copy_arr(smf, yW3, F_YW3, ci * 32, 32, fmode, tid);
    copy_arr(smf, gb1, F_GB1, ci * 32, 32, fmode, tid);
    copy_arr(smf, gb2, F_GB2, ci * 32, 32, fmode, tid);
    copy_arr(smf, gW3, F_GW3, ci * 32, 32, fmode, tid);
    copy_arr(smf, yb3, F_YB3, ci, 1, fmode, tid);
    copy_arr(smf, gb3, F_GB3, ci, 1, fmode, tid);
    __syncthreads();

    const int s2  = tid & 3;
    const int s1l = (tid >> 2) & 1;
    const int n2b = tid >> 3;            // [0,32)
    const int s1  = s1h * 2 + s1l;
    const int b   = bn >> 7;

    const float fb = loadS(g_coset, (bn * SS + s1) * CIN + ci, fmode);

    float fa[4];
    unsigned int gpk[4][4];
    int mbits = 0;
#pragma unroll
    for (int p = 0; p < 4; ++p) {
        const int n2 = n2b + p * 32;
        fa[p] = loadS(g_coset, ((b * NN + n2) * SS + s2) * CIN + ci, fmode);
        const int pos = ((bn * NN + n2) * SS + s1) * SS + s2;
        float g8[8];
        load8(g_pw, pos * DGG, fmode, g8);
#pragma unroll
        for (int q = 0; q < 4; ++q)
            gpk[p][q] = pk2u(g8[2 * q], g8[2 * q + 1]);
        mbits |= load_mask(g_mask, (b * NN + n2) * SS + s2, mmode) << p;
    }

    unsigned int fabpk[4];
#pragma unroll
    for (int p = 0; p < 4; ++p) fabpk[p] = pk2u(fa[p], fb);

    unsigned int h1pk[4][16];
    // ---- ky layer 1 ----
    {
        const unsigned int* W1 = &smu[U_YW1];
        const float* B1 = &smf[F_YB1];
#pragma unroll
        for (int jj = 0; jj < 16; ++jj) {
            float hv[4][2];
#pragma unroll
            for (int e = 0; e < 2; ++e) {
                half2v w = upk(W1[2 * jj + e]);
                float c = B1[2 * jj + e];
#pragma unroll
                for (int p = 0; p < 4; ++p)
                    hv[p][e] = silu_f(FDOT2(w, upk(fabpk[p]), c));
            }
#pragma unroll
            for (int p = 0; p < 4; ++p) h1pk[p][jj] = pk2u(hv[p][0], hv[p][1]);
        }
    }
    // ---- ky layers 2+3 fused ----
    float kyv[4];
    {
        const unsigned int* W2 = &smu[U_YW2];
        const float* B2 = &smf[F_YB2];
        const float* W3 = &smf[F_YW3];
        float a3[4] = {0.f, 0.f, 0.f, 0.f};
#pragma unroll 2
        for (int j = 0; j < HH; ++j) {
            const unsigned int* row = &W2[j * 16];
            float bb = B2[j];
            float d[4] = {bb, bb, bb, bb};
#pragma unroll
            for (int k2 = 0; k2 < 16; ++k2) {
                half2v w = upk(row[k2]);
#pragma unroll
                for (int p = 0; p < 4; ++p) d[p] = FDOT2(w, upk(h1pk[p][k2]), d[p]);
            }
            float w3 = W3[j];
#pragma unroll
            for (int p = 0; p < 4; ++p) a3[p] += w3 * silu_f(d[p]);
        }
        float b3 = smf[F_YB3];
#pragma unroll
        for (int p = 0; p < 4; ++p) kyv[p] = silu_f(a3[p] + b3);
    }
    // ---- kg layer 1 ----
    {
        const unsigned int* W1 = &smu[U_GW1];
        const float* B1 = &smf[F_GB1];
#pragma unroll
        for (int jj = 0; jj < 16; ++jj) {
            float hv[4][2];
#pragma unroll
            for (int e = 0; e < 2; ++e) {
                const unsigned int* r = &W1[(2 * jj + e) * 4];
                float bb = B1[2 * jj + e];
#pragma unroll
                for (int p = 0; p < 4; ++p) {
                    float t = bb;
#pragma unroll
                    for (int q = 0; q < 4; ++q)
                        t = FDOT2(upk(r[q]), upk(gpk[p][q]), t);
                    hv[p][e] = silu_f(t);
                }
            }
#pragma unroll
            for (int p = 0; p < 4; ++p) h1pk[p][jj] = pk2u(hv[p][0], hv[p][1]);
        }
    }
    // ---- kg layers 2+3 fused ----
    float kgv[4];
    {
        const unsigned int* W2 = &smu[U_GW2];
        const float* B2 = &smf[F_GB2];
        const float* W3 = &smf[F_GW3];
        float a3[4] = {0.f, 0.f, 0.f, 0.f};
#pragma unroll 2
        for (int j = 0; j < HH; ++j) {
            const unsigned int* row = &W2[j * 16];
            float bb = B2[j];
            float d[4] = {bb, bb, bb, bb};
#pragma unroll
            for (int k2 = 0; k2 < 16; ++k2) {
                half2v w = upk(row[k2]);
#pragma unroll
                for (int p = 0; p < 4; ++p) d[p] = FDOT2(w, upk(h1pk[p][k2]), d[p]);
            }
            float w3 = W3[j];
#pragma unroll
            for (int p = 0; p < 4; ++p) a3[p] += w3 * silu_f(d[p]);
        }
        float b3 = smf[F_GB3];
#pragma unroll
        for (int p = 0; p < 4; ++p) kgv[p] = silu_f(a3[p] + b3);
    }
    // ---- masked exp, accumulate over positions ----
    float accN = 0.f, accD = 0.f;
#pragma unroll
    for (int p = 0; p < 4; ++p) {
        float e = ((mbits >> p) & 1) ? exp_f(kyv[p] + kgv[p]) : 0.f;
        accD += e;
        accN += e * fa[p];
    }

    // ---- reduce over lane bits {0,1}=s2 and {3,4,5}=n2b-in-wave ----
    accN += __shfl_xor(accN, 1);  accD += __shfl_xor(accD, 1);
    accN += __shfl_xor(accN, 2);  accD += __shfl_xor(accD, 2);
    accN += __shfl_xor(accN, 8);  accD += __shfl_xor(accD, 8);
    accN += __shfl_xor(accN, 16); accD += __shfl_xor(accD, 16);
    accN += __shfl_xor(accN, 32); accD += __shfl_xor(accD, 32);
    const int lane = tid & 63;
    const int wave = tid >> 6;
    if ((lane & 59) == 0) {   // lanes 0,4 hold s1l = 0,1
        const int ps1l = (lane >> 2) & 1;
        smf[F_RED + (wave * 2 + ps1l) * 2 + 0] = accN;
        smf[F_RED + (wave * 2 + ps1l) * 2 + 1] = accD;
    }
    __syncthreads();
    if (tid < 4) {
        const int ps1l = tid >> 1, nd = tid & 1;
        float v = 0.f;
#pragma unroll
        for (int w = 0; w < 4; ++w) v += smf[F_RED + (w * 2 + ps1l) * 2 + nd];
        const int os1 = s1h * 2 + ps1l;
        __hip_atomic_store(&part[(bn * 4 + os1) * 8 + ci * 2 + nd], v,
                           __ATOMIC_RELAXED, __HIP_MEMORY_SCOPE_AGENT);
        __threadfence();
    }
    __syncthreads();

    if (sub != 7) {
        if (tid == 0)
            __hip_atomic_store(&flags[blk], 1u, __ATOMIC_RELEASE,
                               __HIP_MEMORY_SCOPE_AGENT);
        return;
    }

    // ---- finalizer block (sub==7) for this bn ----
    if (tid == 0) {
#pragma unroll 1
        for (int s = 0; s < 7; ++s) {
            const unsigned int* f = &flags[bn * 8 + s];
            while (__hip_atomic_load(f, __ATOMIC_ACQUIRE,
                                     __HIP_MEMORY_SCOPE_AGENT) != 1u)
                __builtin_amdgcn_s_sleep(2);
        }
    }
    __syncthreads();
    if (tid < 32) {
        const int os1 = tid >> 3, o = tid & 7;
        const int m1 = load_mask(g_mask, bn * SS + os1, mmode);
        float v = 0.f;
#pragma unroll
        for (int i2 = 0; i2 < CIN; ++i2) {
            float num = __hip_atomic_load(&part[(bn * 4 + os1) * 8 + i2 * 2],
                                          __ATOMIC_RELAXED, __HIP_MEMORY_SCOPE_AGENT);
            float den = __hip_atomic_load(&part[(bn * 4 + os1) * 8 + i2 * 2 + 1],
                                          __ATOMIC_RELAXED, __HIP_MEMORY_SCOPE_AGENT);
            float fbv = loadS(g_coset, (bn * SS + os1) * CIN + i2, fmode);
            float cf = m1 ? (fbv + num / den) : 0.f;
            v += cf * loadS(wout, o * CIN + i2, fmode);
        }
        const int oidx = (bn * SS + os1) * COUT + o;
        if (fmode) ((__hip_bfloat16*)outp)[oidx] = __float2bfloat16(v);
        else       ((float*)outp)[oidx] = v;
    }
    __syncthreads();
    // reset sibling flags so graph replays are correct even if ws isn't
    // re-poisoned between replays
    if (tid < 7)
        __hip_atomic_store(&flags[bn * 8 + tid], 0xAAAAAAAAu,
                           __ATOMIC_RELAXED, __HIP_MEMORY_SCOPE_AGENT);
}

extern "C" void kernel_launch(void* const* d_in, const int* in_sizes, int n_in,
                              void* d_out, int out_size, void* d_ws, size_t ws_size,
                              hipStream_t stream) {
    float*        part  = (float*)d_ws;                         // 32768 B
    unsigned int* flags = (unsigned int*)((char*)d_ws + 32768); // 8192 B
    emha_fused<<<8 * BB * NN, 256, 0, stream>>>(
        d_in[0], d_in[1], d_in[2],
        d_in[3], d_in[4], d_in[5], d_in[6], d_in[7], d_in[8],
        d_in[9], d_in[10], d_in[11], d_in[12], d_in[13], d_in[14],
        d_in[15], part, flags, d_out);
}

// Round 8
// 239.897 us; speedup vs baseline: 1.1614x; 1.1614x over previous
//
#include <hip/hip_runtime.h>
#include <hip/hip_bf16.h>

#define BB   2
#define NN   128
#define SS   4
#define DGG  8
#define CIN  4
#define COUT 8
#define HH   32

typedef __attribute__((ext_vector_type(4))) float          fvec4;
typedef __attribute__((ext_vector_type(4))) unsigned short usvec4;
typedef __attribute__((ext_vector_type(8))) unsigned short usvec8;
typedef __attribute__((ext_vector_type(2))) __fp16         half2v;
typedef __attribute__((ext_vector_type(4))) unsigned int   uvec4;
typedef __attribute__((ext_vector_type(2))) unsigned int   uvec2;

__device__ __forceinline__ float bf2f(unsigned short u) {
    return __uint_as_float(((unsigned int)u) << 16);
}
__device__ __forceinline__ float silu_f(float x) {
    float e = __builtin_amdgcn_exp2f(x * -1.44269504f);
    return x * __builtin_amdgcn_rcpf(1.0f + e);
}
__device__ __forceinline__ float exp_f(float x) {
    return __builtin_amdgcn_exp2f(x * 1.44269504f);
}

#if __has_builtin(__builtin_amdgcn_fdot2)
__device__ __forceinline__ float FDOT2(half2v a, half2v b, float c) {
    return __builtin_amdgcn_fdot2(a, b, c, false);
}
#else
__device__ __forceinline__ float FDOT2(half2v a, half2v b, float c) {
    return (float)a[0] * (float)b[0] + (float)a[1] * (float)b[1] + c;
}
#endif

__device__ __forceinline__ half2v upk(unsigned int u) {
    union { unsigned int u; half2v h; } x; x.u = u; return x.h;
}
__device__ __forceinline__ unsigned int pk2u(float a, float b) {
#if __has_builtin(__builtin_amdgcn_cvt_pkrtz)
    half2v h = __builtin_amdgcn_cvt_pkrtz(a, b);
#else
    half2v h; h[0] = (__fp16)a; h[1] = (__fp16)b;
#endif
    union { half2v h; unsigned int u; } x; x.h = h; return x.u;
}

__device__ __forceinline__ float loadS(const void* p, int idx, int fmode) {
    return fmode ? bf2f(((const unsigned short*)p)[idx])
                 : ((const float*)p)[idx];
}
__device__ __forceinline__ void load4(const void* p, int base, int fmode, float* dst) {
    if (fmode) {
        usvec4 v = *(const usvec4*)((const unsigned short*)p + base);
        dst[0] = bf2f(v[0]); dst[1] = bf2f(v[1]);
        dst[2] = bf2f(v[2]); dst[3] = bf2f(v[3]);
    } else {
        fvec4 v = *(const fvec4*)((const float*)p + base);
        dst[0] = v[0]; dst[1] = v[1]; dst[2] = v[2]; dst[3] = v[3];
    }
}
__device__ __forceinline__ void load8(const void* p, int base, int fmode, float* dst) {
    if (fmode) {
        usvec8 v = *(const usvec8*)((const unsigned short*)p + base);
#pragma unroll
        for (int d = 0; d < 8; ++d) dst[d] = bf2f(v[d]);
    } else {
        fvec4 a = *(const fvec4*)((const float*)p + base);
        fvec4 b = *(const fvec4*)((const float*)p + base + 4);
        dst[0] = a[0]; dst[1] = a[1]; dst[2] = a[2]; dst[3] = a[3];
        dst[4] = b[0]; dst[5] = b[1]; dst[6] = b[2]; dst[7] = b[3];
    }
}
__device__ __forceinline__ int load_mask(const void* p, int idx, int mmode) {
    if (mmode == 0) return ((const int*)p)[idx] != 0;
    if (mmode == 1) return ((const unsigned short*)p)[idx] != 0;
    if (mmode == 2) return ((const unsigned char*)p)[idx] != 0;
    return ((const unsigned int*)p)[idx] != 0;
}

__device__ __forceinline__ void stage_pk(unsigned int* dst, const void* src,
                                         int pairs, int fmode, int tid) {
    if (fmode) {
        const unsigned short* s = (const unsigned short*)src;
        for (int x = tid; x < pairs; x += 256)
            dst[x] = pk2u(bf2f(s[2 * x]), bf2f(s[2 * x + 1]));
    } else {
        const float* s = (const float*)src;
        for (int x = tid; x < pairs; x += 256)
            dst[x] = pk2u(s[2 * x], s[2 * x + 1]);
    }
}
__device__ __forceinline__ void copy_arr(float* sm, const void* src, int off,
                                         int cnt, int fmode, int tid) {
    if (fmode) {
        const unsigned short* s = (const unsigned short*)src;
        for (int x = tid; x < cnt; x += 256) sm[off + x] = bf2f(s[x]);
    } else {
        const float* s = (const float*)src;
        for (int x = tid; x < cnt; x += 256) sm[off + x] = s[x];
    }
}

// inline dtype detection (wave 0 of every block; deterministic).
// res[0]=fmode (0=f32,1=bf16), res[1]=mask mode (0=i32,1=bf16,2=u8,3=f32)
__device__ __forceinline__ void detect_inline(const void* g_mask, const void* g_coset,
                                              int tid, int* smi, int slot) {
    if (tid < 64) {
        const unsigned short* cu = (const unsigned short*)g_coset;
        unsigned short v = cu[2 * tid];
        int e = (v >> 7) & 0xFF;
        int hits = __popcll(__ballot(e >= 110 && e <= 135));
        int fmode_ = (hits > 32) ? 1 : 0;
        const unsigned short* mu = (const unsigned short*)g_mask;
        int evenBF = 0, any3 = 0, anyByte = 0;
        for (int r = 0; r < 8; ++r) {
            int idx = tid + r * 64;
            unsigned short m = mu[idx];
            if (m == 0x3F80) { any3 = 1; if (!(idx & 1)) evenBF = 1; }
            if (m == 0x0101 || m == 0x0100) anyByte = 1;
        }
        evenBF  = (__ballot(evenBF)  != 0ull);
        any3    = (__ballot(any3)    != 0ull);
        anyByte = (__ballot(anyByte) != 0ull);
        if (tid == 0) {
            smi[slot]     = fmode_;
            smi[slot + 1] = evenBF ? 1 : (any3 ? 3 : (anyByte ? 2 : 0));
        }
    }
}

// LDS layout (u32 units) — round-6 proven layout + mode slots
#define U_YW1  0      // 128  pairs
#define U_GW1  128    // 512  pairs (16B-aligned rows of 4)
#define U_YW2  640    // 2048 pairs (16B-aligned rows of 16)
#define U_GW2  2688   // 2048
#define F_YB1  4736   // 128 floats
#define F_YB2  4864
#define F_YW3  4992
#define F_YB3  5120   // 4
#define F_GB1  5124
#define F_GB2  5252
#define F_GW3  5380
#define F_GB3  5508   // 4
#define F_PART 5512   // 16: [4 waves][2 s1l][2]x2ch... (round-6 scheme: 32)
#define F_MODE 5544   // 2 ints
#define U_TOTAL 5546

// Round-6 proven structure: 1024 blocks = bn*4 + ihalf*2 + s1h; 256 threads
// tid = n2b*8 + s1l*4 + s2; P=4 positions fully unrolled (runtime position
// loops re-trigger scratch spill — round-5 lesson); 2 channels per thread
// (channel-split, not position-split — round-3/7 lessons: finer splits halve
// the body and let fixed costs dominate).  New vs round 6: W2/GW1 rows read
// as uint4 (ds_read_b128, 4x fewer DS instructions on the dominant path) and
// dtype-detect inlined (one fewer serialized launch).
__global__ __launch_bounds__(256, 4) void emha_main(
    const void* __restrict__ g_pw, const void* __restrict__ g_coset,
    const void* __restrict__ g_mask,
    const void* yW1, const void* yb1, const void* yW2, const void* yb2,
    const void* yW3, const void* yb3,
    const void* gW1, const void* gb1, const void* gW2, const void* gb2,
    const void* gW3, const void* gb3,
    float* part)
{
    __shared__ unsigned int smu[U_TOTAL];
    float* smf = (float*)smu;
    int*   smi = (int*)smu;
    const int tid = threadIdx.x;

    detect_inline(g_mask, g_coset, tid, smi, F_MODE);
    __syncthreads();
    const int fmode = smi[F_MODE];
    const int mmode = smi[F_MODE + 1];
    __syncthreads();   // F_MODE slot read before staging overwrites nothing (distinct), but keep order clean

    stage_pk(&smu[U_YW1], yW1, 128,  fmode, tid);
    stage_pk(&smu[U_GW1], gW1, 512,  fmode, tid);
    stage_pk(&smu[U_YW2], yW2, 2048, fmode, tid);
    stage_pk(&smu[U_GW2], gW2, 2048, fmode, tid);
    copy_arr(smf, yb1, F_YB1, 128, fmode, tid);
    copy_arr(smf, yb2, F_YB2, 128, fmode, tid);
    copy_arr(smf, yW3, F_YW3, 128, fmode, tid);
    copy_arr(smf, yb3, F_YB3, 4,   fmode, tid);
    copy_arr(smf, gb1, F_GB1, 128, fmode, tid);
    copy_arr(smf, gb2, F_GB2, 128, fmode, tid);
    copy_arr(smf, gW3, F_GW3, 128, fmode, tid);
    copy_arr(smf, gb3, F_GB3, 4,   fmode, tid);
    __syncthreads();

    const int s2  = tid & 3;
    const int s1l = (tid >> 2) & 1;
    const int n2b = tid >> 3;                 // [0,32)
    const int bn    = blockIdx.x >> 2;
    const int sub   = blockIdx.x & 3;
    const int ihalf = sub >> 1;
    const int s1h   = sub & 1;
    const int s1 = s1h * 2 + s1l;
    const int b  = bn >> 7;

    float fb2[2];
    {
        float r[4];
        load4(g_coset, (bn * SS + s1) * CIN, fmode, r);
        fb2[0] = r[ihalf * 2 + 0];
        fb2[1] = r[ihalf * 2 + 1];
    }

    float fa2[4][2];
    unsigned int gpk[4][4];
    int mbits = 0;
#pragma unroll
    for (int p = 0; p < 4; ++p) {
        const int n2 = n2b + p * 32;
        float r[4];
        load4(g_coset, ((b * NN + n2) * SS + s2) * CIN, fmode, r);
        fa2[p][0] = r[ihalf * 2 + 0];
        fa2[p][1] = r[ihalf * 2 + 1];
        const int pos = ((bn * NN + n2) * SS + s1) * SS + s2;
        float g8[8];
        load8(g_pw, pos * DGG, fmode, g8);
#pragma unroll
        for (int q = 0; q < 4; ++q)
            gpk[p][q] = pk2u(g8[2 * q], g8[2 * q + 1]);
        mbits |= load_mask(g_mask, (b * NN + n2) * SS + s2, mmode) << p;
    }

    float accN[2] = {0.f, 0.f}, accD[2] = {0.f, 0.f};

#pragma unroll
    for (int ii = 0; ii < 2; ++ii) {
        const int i = ihalf * 2 + ii;
        unsigned int fabpk[4];
#pragma unroll
        for (int p = 0; p < 4; ++p) fabpk[p] = pk2u(fa2[p][ii], fb2[ii]);

        unsigned int h1pk[4][16];
        // ---- ky layer 1 ----
        {
            const float* B1 = &smf[F_YB1 + i * HH];
#pragma unroll
            for (int jj = 0; jj < 16; ++jj) {
                uvec2 wpair = *(const uvec2*)&smu[U_YW1 + i * 32 + 2 * jj];
                float hv[4][2];
#pragma unroll
                for (int e = 0; e < 2; ++e) {
                    half2v w = upk(wpair[e]);
                    float c = B1[2 * jj + e];
#pragma unroll
                    for (int p = 0; p < 4; ++p)
                        hv[p][e] = silu_f(FDOT2(w, upk(fabpk[p]), c));
                }
#pragma unroll
                for (int p = 0; p < 4; ++p) h1pk[p][jj] = pk2u(hv[p][0], hv[p][1]);
            }
        }
        // ---- ky layers 2+3 fused (uint4 row loads -> ds_read_b128) ----
        float kyv[4];
        {
            const float* B2 = &smf[F_YB2 + i * HH];
            const float* W3 = &smf[F_YW3 + i * HH];
            float a3[4] = {0.f, 0.f, 0.f, 0.f};
#pragma unroll 2
            for (int j = 0; j < HH; ++j) {
                const uvec4* row = (const uvec4*)&smu[U_YW2 + i * 512 + j * 16];
                float bb = B2[j];
                float d[4] = {bb, bb, bb, bb};
#pragma unroll
                for (int q = 0; q < 4; ++q) {
                    uvec4 rq = row[q];
#pragma unroll
                    for (int e = 0; e < 4; ++e) {
                        half2v w = upk(rq[e]);
#pragma unroll
                        for (int p = 0; p < 4; ++p)
                            d[p] = FDOT2(w, upk(h1pk[p][q * 4 + e]), d[p]);
                    }
                }
                float w3 = W3[j];
#pragma unroll
                for (int p = 0; p < 4; ++p) a3[p] += w3 * silu_f(d[p]);
            }
            float b3 = smf[F_YB3 + i];
#pragma unroll
            for (int p = 0; p < 4; ++p) kyv[p] = silu_f(a3[p] + b3);
        }
        // ---- kg layer 1 (uint4 row loads) ----
        {
            const float* B1 = &smf[F_GB1 + i * HH];
#pragma unroll
            for (int jj = 0; jj < 16; ++jj) {
                float hv[4][2];
#pragma unroll
                for (int e = 0; e < 2; ++e) {
                    uvec4 rr = *(const uvec4*)&smu[U_GW1 + i * 128 + (2 * jj + e) * 4];
                    float bb = B1[2 * jj + e];
#pragma unroll
                    for (int p = 0; p < 4; ++p) {
                        float t = bb;
#pragma unroll
                        for (int q = 0; q < 4; ++q)
                            t = FDOT2(upk(rr[q]), upk(gpk[p][q]), t);
                        hv[p][e] = silu_f(t);
                    }
                }
#pragma unroll
                for (int p = 0; p < 4; ++p) h1pk[p][jj] = pk2u(hv[p][0], hv[p][1]);
            }
        }
        // ---- kg layers 2+3 fused (uint4 row loads) ----
        float kgv[4];
        {
            const float* B2 = &smf[F_GB2 + i * HH];
            const float* W3 = &smf[F_GW3 + i * HH];
            float a3[4] = {0.f, 0.f, 0.f, 0.f};
#pragma unroll 2
            for (int j = 0; j < HH; ++j) {
                const uvec4* row = (const uvec4*)&smu[U_GW2 + i * 512 + j * 16];
                float bb = B2[j];
                float d[4] = {bb, bb, bb, bb};
#pragma unroll
                for (int q = 0; q < 4; ++q) {
                    uvec4 rq = row[q];
#pragma unroll
                    for (int e = 0; e < 4; ++e) {
                        half2v w = upk(rq[e]);
#pragma unroll
                        for (int p = 0; p < 4; ++p)
                            d[p] = FDOT2(w, upk(h1pk[p][q * 4 + e]), d[p]);
                    }
                }
                float w3 = W3[j];
#pragma unroll
                for (int p = 0; p < 4; ++p) a3[p] += w3 * silu_f(d[p]);
            }
            float b3 = smf[F_GB3 + i];
#pragma unroll
            for (int p = 0; p < 4; ++p) kgv[p] = silu_f(a3[p] + b3);
        }
        // ---- masked exp, accumulate ----
#pragma unroll
        for (int p = 0; p < 4; ++p) {
            float e = ((mbits >> p) & 1) ? exp_f(kyv[p] + kgv[p]) : 0.f;
            accD[ii] += e;
            accN[ii] += e * fa2[p][ii];
        }
    }

    // reduce over lane bits {0,1}=s2 and {3,4,5}=n2b-in-wave
#pragma unroll
    for (int ii = 0; ii < 2; ++ii) {
        accN[ii] += __shfl_xor(accN[ii], 1);
        accD[ii] += __shfl_xor(accD[ii], 1);
        accN[ii] += __shfl_xor(accN[ii], 2);
        accD[ii] += __shfl_xor(accD[ii], 2);
        accN[ii] += __shfl_xor(accN[ii], 8);
        accD[ii] += __shfl_xor(accD[ii], 8);
        accN[ii] += __shfl_xor(accN[ii], 16);
        accD[ii] += __shfl_xor(accD[ii], 16);
        accN[ii] += __shfl_xor(accN[ii], 32);
        accD[ii] += __shfl_xor(accD[ii], 32);
    }
    const int lane = tid & 63;
    const int wave = tid >> 6;
    if ((lane & 59) == 0) {   // lanes 0,4 hold s1l = 0,1
        const int ps1l = (lane >> 2) & 1;
        float* pp = &smf[F_PART + (wave * 2 + ps1l) * 4];
        pp[0] = accN[0]; pp[1] = accD[0]; pp[2] = accN[1]; pp[3] = accD[1];
    }
    __syncthreads();
    if (tid < 8) {
        const int ps1l = tid >> 2, q = tid & 3;
        float v = 0.f;
#pragma unroll
        for (int w = 0; w < 4; ++w) v += smf[F_PART + (w * 2 + ps1l) * 4 + q];
        const int i = ihalf * 2 + (q >> 1);
        const int nd = q & 1;
        const int os1 = s1h * 2 + ps1l;
        part[(bn * 4 + os1) * 8 + i * 2 + nd] = v;
    }
}

// ===================== finalize ============================================
__global__ void finalize_kernel(const void* __restrict__ g_coset,
                                const void* __restrict__ g_mask,
                                const void* wout, const float* part,
                                void* outp) {
    __shared__ int smi[2];
    const int tid = threadIdx.x;
    detect_inline(g_mask, g_coset, tid, smi, 0);
    __syncthreads();
    const int fmode = smi[0], mmode = smi[1];

    const int t = blockIdx.x * 256 + tid;  // [0,1024)
    const int bn = t >> 2;
    const int s1 = t & 3;

    float fb[4];
    load4(g_coset, (bn * SS + s1) * CIN, fmode, fb);
    const int m1 = load_mask(g_mask, bn * SS + s1, mmode);

    float cf[4];
#pragma unroll
    for (int i = 0; i < CIN; ++i) {
        float num = part[(bn * 4 + s1) * 8 + i * 2];
        float den = part[(bn * 4 + s1) * 8 + i * 2 + 1];
        cf[i] = m1 ? (fb[i] + num / den) : 0.f;
    }
#pragma unroll
    for (int o = 0; o < COUT; ++o) {
        float wv[4];
        load4(wout, o * CIN, fmode, wv);
        float v = cf[0] * wv[0] + cf[1] * wv[1] + cf[2] * wv[2] + cf[3] * wv[3];
        const int oidx = (bn * SS + s1) * COUT + o;
        if (fmode) ((__hip_bfloat16*)outp)[oidx] = __float2bfloat16(v);
        else       ((float*)outp)[oidx] = v;
    }
}

extern "C" void kernel_launch(void* const* d_in, const int* in_sizes, int n_in,
                              void* d_out, int out_size, void* d_ws, size_t ws_size,
                              hipStream_t stream) {
    float* part = (float*)d_ws;   // 1024*8 floats = 32 KB
    emha_main<<<4 * BB * NN, 256, 0, stream>>>(
        d_in[0], d_in[1], d_in[2],
        d_in[3], d_in[4], d_in[5], d_in[6], d_in[7], d_in[8],
        d_in[9], d_in[10], d_in[11], d_in[12], d_in[13], d_in[14],
        part);
    finalize_kernel<<<4, 256, 0, stream>>>(d_in[1], d_in[2], d_in[15], part,
                                           d_out);
}

// Round 10
// 195.314 us; speedup vs baseline: 1.4266x; 1.2283x over previous
//
#include <hip/hip_runtime.h>
#include <hip/hip_bf16.h>

#define BB   2
#define NN   128
#define SS   4
#define DGG  8
#define CIN  4
#define COUT 8
#define HH   32

typedef __attribute__((ext_vector_type(4))) float          fvec4;
typedef __attribute__((ext_vector_type(4))) unsigned short usvec4;
typedef __attribute__((ext_vector_type(8))) unsigned short usvec8;
typedef __attribute__((ext_vector_type(2))) __fp16         half2v;
typedef __attribute__((ext_vector_type(8))) __fp16         f16x8;
typedef __attribute__((ext_vector_type(4))) float          f32x4;
typedef __attribute__((ext_vector_type(4))) unsigned int   uvec4;

__device__ __forceinline__ float bf2f(unsigned short u) {
    return __uint_as_float(((unsigned int)u) << 16);
}
__device__ __forceinline__ float silu_f(float x) {
    float e = __builtin_amdgcn_exp2f(x * -1.44269504f);
    return x * __builtin_amdgcn_rcpf(1.0f + e);
}
__device__ __forceinline__ float exp_f(float x) {
    return __builtin_amdgcn_exp2f(x * 1.44269504f);
}

#if __has_builtin(__builtin_amdgcn_fdot2)
__device__ __forceinline__ float FDOT2(half2v a, half2v b, float c) {
    return __builtin_amdgcn_fdot2(a, b, c, false);
}
#else
__device__ __forceinline__ float FDOT2(half2v a, half2v b, float c) {
    return (float)a[0] * (float)b[0] + (float)a[1] * (float)b[1] + c;
}
#endif

__device__ __forceinline__ half2v upk(unsigned int u) {
    union { unsigned int u; half2v h; } x; x.u = u; return x.h;
}
__device__ __forceinline__ unsigned int pk2u(float a, float b) {
#if __has_builtin(__builtin_amdgcn_cvt_pkrtz)
    half2v h = __builtin_amdgcn_cvt_pkrtz(a, b);
#else
    half2v h; h[0] = (__fp16)a; h[1] = (__fp16)b;
#endif
    union { half2v h; unsigned int u; } x; x.h = h; return x.u;
}
union FU { uvec4 u; f16x8 h; };
__device__ __forceinline__ f16x8 mk_frag(unsigned a, unsigned b, unsigned c, unsigned d) {
    FU x; x.u = (uvec4){a, b, c, d}; return x.h;
}

__device__ __forceinline__ float loadS(const void* p, int idx, int fmode) {
    return fmode ? bf2f(((const unsigned short*)p)[idx])
                 : ((const float*)p)[idx];
}
__device__ __forceinline__ void load8(const void* p, int base, int fmode, float* dst) {
    if (fmode) {
        usvec8 v = *(const usvec8*)((const unsigned short*)p + base);
#pragma unroll
        for (int d = 0; d < 8; ++d) dst[d] = bf2f(v[d]);
    } else {
        fvec4 a = *(const fvec4*)((const float*)p + base);
        fvec4 b = *(const fvec4*)((const float*)p + base + 4);
        dst[0] = a[0]; dst[1] = a[1]; dst[2] = a[2]; dst[3] = a[3];
        dst[4] = b[0]; dst[5] = b[1]; dst[6] = b[2]; dst[7] = b[3];
    }
}
// 8 consecutive weights -> f16x8 MFMA fragment (element r = k offset r)
__device__ __forceinline__ f16x8 load_row8(const void* p, int eoff, int fmode) {
    unsigned u[4];
    if (fmode) {
        usvec8 v = *(const usvec8*)((const unsigned short*)p + eoff);
#pragma unroll
        for (int q = 0; q < 4; ++q) u[q] = pk2u(bf2f(v[2 * q]), bf2f(v[2 * q + 1]));
    } else {
        fvec4 a = *(const fvec4*)((const float*)p + eoff);
        fvec4 b = *(const fvec4*)((const float*)p + eoff + 4);
        u[0] = pk2u(a[0], a[1]); u[1] = pk2u(a[2], a[3]);
        u[2] = pk2u(b[0], b[1]); u[3] = pk2u(b[2], b[3]);
    }
    return mk_frag(u[0], u[1], u[2], u[3]);
}
__device__ __forceinline__ int load_mask(const void* p, int idx, int mmode) {
    if (mmode == 0) return ((const int*)p)[idx] != 0;
    if (mmode == 1) return ((const unsigned short*)p)[idx] != 0;
    if (mmode == 2) return ((const unsigned char*)p)[idx] != 0;
    return ((const unsigned int*)p)[idx] != 0;
}
__device__ __forceinline__ void stage_pk(unsigned int* dst, const void* src,
                                         int pairs, int fmode, int tid) {
    if (fmode) {
        const unsigned short* s = (const unsigned short*)src;
        for (int x = tid; x < pairs; x += 256)
            dst[x] = pk2u(bf2f(s[2 * x]), bf2f(s[2 * x + 1]));
    } else {
        const float* s = (const float*)src;
        for (int x = tid; x < pairs; x += 256)
            dst[x] = pk2u(s[2 * x], s[2 * x + 1]);
    }
}
__device__ __forceinline__ void copy_arr(float* sm, const void* src, int off,
                                         int cnt, int fmode, int tid) {
    if (fmode) {
        const unsigned short* s = (const unsigned short*)src;
        for (int x = tid; x < cnt; x += 256) sm[off + x] = bf2f(s[x]);
    } else {
        const float* s = (const float*)src;
        for (int x = tid; x < cnt; x += 256) sm[off + x] = s[x];
    }
}
// modes: [0]=float dtype (0=f32,1=bf16), [1]=mask dtype (0=i32,1=bf16,2=u8,3=f32)
__device__ __forceinline__ void detect_inline(const void* g_mask, const void* g_coset,
                                              int tid, int* smi, int slot) {
    if (tid < 64) {
        const unsigned short* cu = (const unsigned short*)g_coset;
        unsigned short v = cu[2 * tid];
        int e = (v >> 7) & 0xFF;
        int hits = __popcll(__ballot(e >= 110 && e <= 135));
        int fmode_ = (hits > 32) ? 1 : 0;
        const unsigned short* mu = (const unsigned short*)g_mask;
        int evenBF = 0, any3 = 0, anyByte = 0;
        for (int r = 0; r < 8; ++r) {
            int idx = tid + r * 64;
            unsigned short m = mu[idx];
            if (m == 0x3F80) { any3 = 1; if (!(idx & 1)) evenBF = 1; }
            if (m == 0x0101 || m == 0x0100) anyByte = 1;
        }
        evenBF  = (__ballot(evenBF)  != 0ull);
        any3    = (__ballot(any3)    != 0ull);
        anyByte = (__ballot(anyByte) != 0ull);
        if (tid == 0) {
            smi[slot]     = fmode_;
            smi[slot + 1] = evenBF ? 1 : (any3 ? 3 : (anyByte ? 2 : 0));
        }
    }
}

// LDS layout (u32 units)
#define UG_G    0      // 2048: pairwise_g slice for (bn,s1), packed f16 [pos][4]
#define F_FA    2048   // 2048 f32: coset b-slice [pos2=n*4+s][ci]
#define U_MASK  4096   // 512: key mask per pos (0/1)
#define U_YW1   4608   // 128 pairs (w0,w1) per (ci,j1)
#define U_GW1   4736   // 512 pairs: [ci][j1][4]
#define F_YB1   5248   // 128
#define F_YB2   5376   // 128
#define F_YW3   5504   // 128
#define F_GB1   5632   // 128
#define F_GB2   5760   // 128
#define F_GW3   5888   // 128
#define F_YB3   6016   // 4
#define F_GB3   6020   // 4
#define F_RED   6024   // 32: [wave][ci][N,D]
#define F_MODE  6056   // 2
#define U_TOTAL 6058   // ~24.2 KB

// One block per (bn, s1); 256 threads = 4 waves; wave handles 8 position-
// tiles of 16 (pos = n2*4+s2 in [0,512)).  Layer-1 MLPs are computed per-lane
// DIRECTLY in MFMA B-layout (B[k=quad*8+j][n=lane&15]); W2 sits in A-frags
// (A[m=lane&15][k=quad*8+j], loaded once per channel); layer-2 GEMMs run on
// v_mfma_f32_16x16x32_f16 (C/D: row=quad*4+reg, col=lane&15 — HW-verified
// mapping).  L3 = per-lane fma + shfl_xor(16,32) over the quad-distributed
// rows.  Block owns the whole (n2,s2) softmax reduction -> writes its 8
// outputs directly (no workspace, no finalize launch).
// NOTE: MFMA call guarded by __HIP_DEVICE_COMPILE__ — the host parsing pass
// doesn't know amdgcn builtins (round-9 compile failure: #error fired on the
// host pass and cascaded into undeclared-identifier errors).
__global__ __launch_bounds__(256, 4) void emha_mfma(
    const void* __restrict__ g_pw, const void* __restrict__ g_coset,
    const void* __restrict__ g_mask,
    const void* yW1, const void* yb1, const void* yW2, const void* yb2,
    const void* yW3, const void* yb3,
    const void* gW1, const void* gb1, const void* gW2, const void* gb2,
    const void* gW3, const void* gb3,
    const void* wout, void* outp)
{
    __shared__ unsigned int smu[U_TOTAL];
    float* smf = (float*)smu;
    int*   smi = (int*)smu;
    const int tid = threadIdx.x;

    detect_inline(g_mask, g_coset, tid, smi, F_MODE);
    __syncthreads();
    const int fmode = smi[F_MODE];
    const int mmode = smi[F_MODE + 1];
    __syncthreads();

    const int bn = blockIdx.x >> 2;   // b*128 + n1
    const int s1 = blockIdx.x & 3;
    const int b  = bn >> 7;
    const int n1 = bn & 127;

    // ---- stage pairwise_g slice (pos = n2*4+s2), packed f16 ----
#pragma unroll
    for (int it = 0; it < 2; ++it) {
        const int pos = tid + it * 256;
        const int n2 = pos >> 2, s2 = pos & 3;
        float g8[8];
        load8(g_pw, (((bn * NN + n2) * SS + s1) * SS + s2) * DGG, fmode, g8);
#pragma unroll
        for (int q = 0; q < 4; ++q)
            smu[UG_G + pos * 4 + q] = pk2u(g8[2 * q], g8[2 * q + 1]);
    }
    // ---- stage coset b-slice (f32) and key mask ----
    for (int x = tid; x < 2048; x += 256)
        smf[F_FA + x] = loadS(g_coset, b * 2048 + x, fmode);
    for (int x = tid; x < 512; x += 256)
        smu[U_MASK + x] = (unsigned)load_mask(g_mask, b * 512 + x, mmode);
    // ---- stage W1s (packed pairs) + biases/w3 (f32) ----
    stage_pk(&smu[U_YW1], yW1, 128, fmode, tid);
    stage_pk(&smu[U_GW1], gW1, 512, fmode, tid);
    copy_arr(smf, yb1, F_YB1, 128, fmode, tid);
    copy_arr(smf, yb2, F_YB2, 128, fmode, tid);
    copy_arr(smf, yW3, F_YW3, 128, fmode, tid);
    copy_arr(smf, gb1, F_GB1, 128, fmode, tid);
    copy_arr(smf, gb2, F_GB2, 128, fmode, tid);
    copy_arr(smf, gW3, F_GW3, 128, fmode, tid);
    copy_arr(smf, yb3, F_YB3, 4, fmode, tid);
    copy_arr(smf, gb3, F_GB3, 4, fmode, tid);
    __syncthreads();

    const int lane = tid & 63;
    const int wave = tid >> 6;
    const int quad = lane >> 4;
    const int col  = lane & 15;
    const int qpos = n1 * 4 + s1;     // query index in b-slice

    float accN[4] = {0.f, 0.f, 0.f, 0.f};
    float accD[4] = {0.f, 0.f, 0.f, 0.f};
    const f32x4 zf = {0.f, 0.f, 0.f, 0.f};

#pragma unroll
    for (int ci = 0; ci < CIN; ++ci) {
        const float fb = smf[F_FA + qpos * 4 + ci];
        // ky L1 constants for this lane's 8 j1 rows (j1 = quad*8 + jj)
        float w0f[8], cc[8], b1g[8];
        {
            uvec4 pa = *(const uvec4*)&smu[U_YW1 + ci * 32 + quad * 8];
            uvec4 pb = *(const uvec4*)&smu[U_YW1 + ci * 32 + quad * 8 + 4];
            fvec4 ba = *(const fvec4*)&smf[F_YB1 + ci * 32 + quad * 8];
            fvec4 bb = *(const fvec4*)&smf[F_YB1 + ci * 32 + quad * 8 + 4];
            fvec4 ga = *(const fvec4*)&smf[F_GB1 + ci * 32 + quad * 8];
            fvec4 gb = *(const fvec4*)&smf[F_GB1 + ci * 32 + quad * 8 + 4];
#pragma unroll
            for (int jj = 0; jj < 4; ++jj) {
                half2v w = upk(pa[jj]);
                w0f[jj] = (float)w[0];
                cc[jj]  = (float)w[1] * fb + ba[jj];
                b1g[jj] = ga[jj];
            }
#pragma unroll
            for (int jj = 0; jj < 4; ++jj) {
                half2v w = upk(pb[jj]);
                w0f[4 + jj] = (float)w[0];
                cc[4 + jj]  = (float)w[1] * fb + bb[jj];
                b1g[4 + jj] = gb[jj];
            }
        }
        // W2 A-fragments: A[m=col(+16)][k=quad*8..+7], direct from global
        const f16x8 Ay0 = load_row8(yW2, ci * 1024 + col * 32 + quad * 8, fmode);
        const f16x8 Ay1 = load_row8(yW2, ci * 1024 + (col + 16) * 32 + quad * 8, fmode);
        const f16x8 Ag0 = load_row8(gW2, ci * 1024 + col * 32 + quad * 8, fmode);
        const f16x8 Ag1 = load_row8(gW2, ci * 1024 + (col + 16) * 32 + quad * 8, fmode);
        const float b3y = smf[F_YB3 + ci];
        const float b3g = smf[F_GB3 + ci];

#pragma unroll 1
        for (int t = 0; t < 8; ++t) {
            const int pos = (wave * 8 + t) * 16 + col;
            const float fap = smf[F_FA + pos * 4 + ci];
            const unsigned km = smu[U_MASK + pos];
            const uvec4 gq = *(const uvec4*)&smu[UG_G + pos * 4];

            // ky L1 -> B-frag (B[k=quad*8+j][n=col])
            unsigned by0 = pk2u(silu_f(w0f[0] * fap + cc[0]), silu_f(w0f[1] * fap + cc[1]));
            unsigned by1 = pk2u(silu_f(w0f[2] * fap + cc[2]), silu_f(w0f[3] * fap + cc[3]));
            unsigned by2 = pk2u(silu_f(w0f[4] * fap + cc[4]), silu_f(w0f[5] * fap + cc[5]));
            unsigned by3 = pk2u(silu_f(w0f[6] * fap + cc[6]), silu_f(w0f[7] * fap + cc[7]));
            const f16x8 By = mk_frag(by0, by1, by2, by3);

            // kg L1 -> B-frag
            unsigned bg[4];
#pragma unroll
            for (int jj2 = 0; jj2 < 4; ++jj2) {
                float hh[2];
#pragma unroll
                for (int e = 0; e < 2; ++e) {
                    const int j1 = quad * 8 + 2 * jj2 + e;
                    uvec4 wr = *(const uvec4*)&smu[U_GW1 + ci * 128 + j1 * 4];
                    float tt = b1g[2 * jj2 + e];
                    tt = FDOT2(upk(wr[0]), upk(gq[0]), tt);
                    tt = FDOT2(upk(wr[1]), upk(gq[1]), tt);
                    tt = FDOT2(upk(wr[2]), upk(gq[2]), tt);
                    tt = FDOT2(upk(wr[3]), upk(gq[3]), tt);
                    hh[e] = silu_f(tt);
                }
                bg[jj2] = pk2u(hh[0], hh[1]);
            }
            const f16x8 Bg = mk_frag(bg[0], bg[1], bg[2], bg[3]);

            f32x4 dy0, dy1, dg0, dg1;
#if defined(__HIP_DEVICE_COMPILE__)
            dy0 = __builtin_amdgcn_mfma_f32_16x16x32_f16(Ay0, By, zf, 0, 0, 0);
            dy1 = __builtin_amdgcn_mfma_f32_16x16x32_f16(Ay1, By, zf, 0, 0, 0);
            dg0 = __builtin_amdgcn_mfma_f32_16x16x32_f16(Ag0, Bg, zf, 0, 0, 0);
            dg1 = __builtin_amdgcn_mfma_f32_16x16x32_f16(Ag1, Bg, zf, 0, 0, 0);
#else
            dy0 = zf; dy1 = zf; dg0 = zf; dg1 = zf;  // host parse only
#endif
            // post-L2 + L3: lane holds rows j2 = quad*4+r (+16 for tile 1),
            // column = its position
            fvec4 b2y0 = *(const fvec4*)&smf[F_YB2 + ci * 32 + quad * 4];
            fvec4 b2y1 = *(const fvec4*)&smf[F_YB2 + ci * 32 + 16 + quad * 4];
            fvec4 w3y0 = *(const fvec4*)&smf[F_YW3 + ci * 32 + quad * 4];
            fvec4 w3y1 = *(const fvec4*)&smf[F_YW3 + ci * 32 + 16 + quad * 4];
            fvec4 b2g0 = *(const fvec4*)&smf[F_GB2 + ci * 32 + quad * 4];
            fvec4 b2g1 = *(const fvec4*)&smf[F_GB2 + ci * 32 + 16 + quad * 4];
            fvec4 w3g0 = *(const fvec4*)&smf[F_GW3 + ci * 32 + quad * 4];
            fvec4 w3g1 = *(const fvec4*)&smf[F_GW3 + ci * 32 + 16 + quad * 4];
            float a3y = 0.f, a3g = 0.f;
#pragma unroll
            for (int r = 0; r < 4; ++r) {
                a3y += w3y0[r] * silu_f(dy0[r] + b2y0[r]);
                a3y += w3y1[r] * silu_f(dy1[r] + b2y1[r]);
                a3g += w3g0[r] * silu_f(dg0[r] + b2g0[r]);
                a3g += w3g1[r] * silu_f(dg1[r] + b2g1[r]);
            }
            a3y += __shfl_xor(a3y, 16); a3y += __shfl_xor(a3y, 32);
            a3g += __shfl_xor(a3g, 16); a3g += __shfl_xor(a3g, 32);

            const float kyv = silu_f(a3y + b3y);
            const float kgv = silu_f(a3g + b3g);
            const float e = km ? exp_f(kyv + kgv) : 0.f;
            accD[ci] += e;
            accN[ci] += e * fap;
        }
    }

    // reduce across the 16 positions (lane bits 0-3; quads hold identical
    // copies after the xor-16/32 reduction, so only reduce bits 0-3 and read
    // from lane 0)
#pragma unroll
    for (int ci = 0; ci < CIN; ++ci) {
        accN[ci] += __shfl_xor(accN[ci], 1);  accD[ci] += __shfl_xor(accD[ci], 1);
        accN[ci] += __shfl_xor(accN[ci], 2);  accD[ci] += __shfl_xor(accD[ci], 2);
        accN[ci] += __shfl_xor(accN[ci], 4);  accD[ci] += __shfl_xor(accD[ci], 4);
        accN[ci] += __shfl_xor(accN[ci], 8);  accD[ci] += __shfl_xor(accD[ci], 8);
    }
    if (lane == 0) {
#pragma unroll
        for (int ci = 0; ci < CIN; ++ci) {
            smf[F_RED + (wave * 4 + ci) * 2 + 0] = accN[ci];
            smf[F_RED + (wave * 4 + ci) * 2 + 1] = accD[ci];
        }
    }
    __syncthreads();

    if (tid < COUT) {
        const int o = tid;
        const unsigned m1 = smu[U_MASK + qpos];
        float acc = 0.f;
#pragma unroll
        for (int ci = 0; ci < CIN; ++ci) {
            float N = 0.f, D = 0.f;
#pragma unroll
            for (int w = 0; w < 4; ++w) {
                N += smf[F_RED + (w * 4 + ci) * 2 + 0];
                D += smf[F_RED + (w * 4 + ci) * 2 + 1];
            }
            const float fbv = smf[F_FA + qpos * 4 + ci];
            const float cf = m1 ? (fbv + N / D) : 0.f;
            acc += cf * loadS(wout, o * CIN + ci, fmode);
        }
        const int oidx = (bn * SS + s1) * COUT + o;
        if (fmode) ((__hip_bfloat16*)outp)[oidx] = __float2bfloat16(acc);
        else       ((float*)outp)[oidx] = acc;
    }
}

extern "C" void kernel_launch(void* const* d_in, const int* in_sizes, int n_in,
                              void* d_out, int out_size, void* d_ws, size_t ws_size,
                              hipStream_t stream) {
    emha_mfma<<<BB * NN * SS, 256, 0, stream>>>(
        d_in[0], d_in[1], d_in[2],
        d_in[3], d_in[4], d_in[5], d_in[6], d_in[7], d_in[8],
        d_in[9], d_in[10], d_in[11], d_in[12], d_in[13], d_in[14],
        d_in[15], d_out);
}